// Round 7
// baseline (214.427 us; speedup 1.0000x reference)
//
#include <hip/hip_runtime.h>

// VQ-VAE vector quantizer, round 7: split-bf16 MFMA, max independent waves, zero spills.
// Clean discriminating experiment after R3-R6 all hit ~100-125us with idle pipes:
//   - NPB=64 -> 1024 blocks = 4 blocks/CU; launch_bounds(256,2) so the compiler does NOT
//     shrink to 64 VGPR + spill (R5/R6 pathology; WRITE_SIZE is the spill canary)
//   - no LDS, no __syncthreads before the epilogue: A-frags converted inline from `in`,
//     B-frags/hsq loaded directly from ws (prep-converted); 64 independent 6-MFMA groups
//   - rescan in two register-halves (<=32 live acc regs), epilogue spread over 256 threads
// out (fp32 concat): [ loss(1) | quantized NCHW (4194304) | indices as float (65536) ]

#define DIMS   64
#define HW     4096
#define NPTS   65536
#define NCODES 1024
#define NPB    64
#define QOFF   1
#define IOFF   (1 + NPTS * DIMS)
#define EPSGAP 1.0e-3f

typedef unsigned int uint;
typedef unsigned short ushort;
typedef unsigned long long ull;
typedef __attribute__((ext_vector_type(8))) short short8;
typedef __attribute__((ext_vector_type(4))) float f32x4;

__device__ __forceinline__ ushort bf16_rne(float f) {
    uint u = __float_as_uint(f);
    uint r = u + 0x7FFFu + ((u >> 16) & 1u);
    return (ushort)(r >> 16);
}
__device__ __forceinline__ float bf16f(ushort h) { return __uint_as_float(((uint)h) << 16); }

// ---- prep: emb fp32 -> {Eh, El bf16 [1024][64]}, hsq = 0.5||e||^2, zero out[0]
__global__ void vq_prep(const float* __restrict__ emb, ushort* __restrict__ Eh,
                        ushort* __restrict__ El, float* __restrict__ hsq,
                        float* __restrict__ out)
{
    const int t = blockIdx.x * 256 + threadIdx.x;      // 0..16383, one float4 each
    if (t == 0) out[0] = 0.f;
    float4 v = ((const float4*)emb)[t];
    ushort h0 = bf16_rne(v.x), h1 = bf16_rne(v.y), h2 = bf16_rne(v.z), h3 = bf16_rne(v.w);
    ushort l0 = bf16_rne(v.x - bf16f(h0)), l1 = bf16_rne(v.y - bf16f(h1));
    ushort l2 = bf16_rne(v.z - bf16f(h2)), l3 = bf16_rne(v.w - bf16f(h3));
    uint2 hp, lp;
    hp.x = (uint)h0 | ((uint)h1 << 16); hp.y = (uint)h2 | ((uint)h3 << 16);
    lp.x = (uint)l0 | ((uint)l1 << 16); lp.y = (uint)l2 | ((uint)l3 << 16);
    *(uint2*)(Eh + (size_t)t * 4) = hp;
    *(uint2*)(El + (size_t)t * 4) = lp;
    if (t < NCODES) {
        const float4* r = (const float4*)(emb + (size_t)t * DIMS);
        float s = 0.f;
        #pragma unroll
        for (int i = 0; i < 16; ++i) {
            float4 e = r[i];
            s = fmaf(e.x, e.x, s); s = fmaf(e.y, e.y, s);
            s = fmaf(e.z, e.z, s); s = fmaf(e.w, e.w, s);
        }
        hsq[t] = 0.5f * s;
    }
}

__launch_bounds__(256, 2)
__global__ void vq_main(const float* __restrict__ in, const float* __restrict__ emb,
                        const ushort* __restrict__ Ehw, const ushort* __restrict__ Elw,
                        const float* __restrict__ hsqw, float* __restrict__ out)
{
    __shared__ float sv1[NPB];
    __shared__ float sv2[NPB];
    __shared__ int   si1[NPB];
    __shared__ ull   msk;
    __shared__ int   lst[1 + NPB];
    __shared__ float lred[4];

    const int tid = threadIdx.x;
    const int lane = tid & 63, w = tid >> 6;
    const int m = lane & 15, quad = lane >> 4;
    const int n0 = blockIdx.x * NPB;
    const int b = n0 >> 12, off = n0 & 4095;           // 64 | 4096: never crosses a batch
    const float* xbase = in + (size_t)b * (DIMS * HW) + off;

    // ---- A fragments inline from global `in` (one-time, ~16 loads + ~130 VALU)
    short8 Ah[2], Al[2];
    {
        const int p = w * 16 + m;
        #pragma unroll
        for (int ks = 0; ks < 2; ++ks) {
            union { ushort u[8]; short8 v; } th, tl;
            #pragma unroll
            for (int j = 0; j < 8; ++j) {
                float x = xbase[(ks * 32 + quad * 8 + j) * HW + p];
                ushort h = bf16_rne(x);
                th.u[j] = h;
                tl.u[j] = bf16_rne(x - bf16f(h));
            }
            Ah[ks] = th.v; Al[ks] = tl.v;
        }
    }

    float v1s[4], v2s[4]; int i1s[4];
    #pragma unroll
    for (int s = 0; s < 4; ++s) { v1s[s] = 1e30f; v2s[s] = 1e30f; i1s[s] = 0; }

    // ---- barrier-free K-loop: 64 independent groups of 16 codes, K=64, 6-MFMA chains
    #pragma unroll 2
    for (int g = 0; g < 64; ++g) {
        const int ca = g * 16 + m;                     // this lane's code id
        const size_t eb = (size_t)ca * 64 + quad * 8;
        short8 Bh0 = *(const short8*)(Ehw + eb);
        short8 Bh1 = *(const short8*)(Ehw + eb + 32);
        short8 Bl0 = *(const short8*)(Elw + eb);
        short8 Bl1 = *(const short8*)(Elw + eb + 32);
        const float ha = hsqw[ca];
        f32x4 acc = {0.f, 0.f, 0.f, 0.f};
        acc = __builtin_amdgcn_mfma_f32_16x16x32_bf16(Ah[0], Bh0, acc, 0, 0, 0);
        acc = __builtin_amdgcn_mfma_f32_16x16x32_bf16(Ah[1], Bh1, acc, 0, 0, 0);
        acc = __builtin_amdgcn_mfma_f32_16x16x32_bf16(Ah[0], Bl0, acc, 0, 0, 0);
        acc = __builtin_amdgcn_mfma_f32_16x16x32_bf16(Ah[1], Bl1, acc, 0, 0, 0);
        acc = __builtin_amdgcn_mfma_f32_16x16x32_bf16(Al[0], Bh0, acc, 0, 0, 0);
        acc = __builtin_amdgcn_mfma_f32_16x16x32_bf16(Al[1], Bh1, acc, 0, 0, 0);
        #pragma unroll
        for (int r = 0; r < 4; ++r) {                  // point = w*16 + quad*4 + r
            float d = ha - acc[r];
            v2s[r] = fminf(v2s[r], fmaxf(d, v1s[r]));  // exact streaming 2nd-min
            bool c2 = d < v1s[r];                      // strict: ascending ca keeps lowest idx
            i1s[r] = c2 ? ca : i1s[r];
            v1s[r] = fminf(d, v1s[r]);
        }
    }

    // ---- merge across the 16 code-lanes (each wave owns its 16 points entirely)
    #pragma unroll
    for (int st = 1; st < 16; st <<= 1) {
        #pragma unroll
        for (int s = 0; s < 4; ++s) {
            float ov1 = __shfl_xor(v1s[s], st);
            float ov2 = __shfl_xor(v2s[s], st);
            int   oi1 = __shfl_xor(i1s[s], st);
            v2s[s] = fminf(fminf(v2s[s], ov2), fmaxf(v1s[s], ov1));
            bool c = (ov1 < v1s[s]) || (ov1 == v1s[s] && oi1 < i1s[s]);
            if (c) i1s[s] = oi1;
            v1s[s] = fminf(v1s[s], ov1);
        }
    }
    if (m == 0) {
        #pragma unroll
        for (int s = 0; s < 4; ++s) {
            int p = w * 16 + quad * 4 + s;
            sv1[p] = v1s[s]; si1[p] = i1s[s]; sv2[p] = v2s[s];
        }
    }
    __syncthreads();

    // ---- flag near-ties (wave 0's 64 lanes = 64 points)
    if (w == 0) {
        bool f = (sv2[lane] - sv1[lane]) < EPSGAP;
        ull bm = __ballot(f);
        if (lane == 0) msk = bm;
    }
    __syncthreads();
    if (tid == 0) {
        int c = 0;
        ull m0 = msk;
        while (m0) { lst[1 + c++] = __ffsll(m0) - 1; m0 &= m0 - 1; }
        lst[0] = c;
    }
    __syncthreads();

    // ---- exact fp32 rescan, one wave per flagged point; two halves cap live regs
    const int cnt = lst[0];
    const float4* e4 = (const float4*)emb;
    for (int it = w; it < cnt; it += 4) {
        const int p = lst[1 + it];
        float xv = xbase[lane * HW + p];               // lane d holds x_d (exact fp32)
        float bv = 1e30f; int bk = 0;
        #pragma unroll
        for (int half = 0; half < 2; ++half) {
            float dacc[8], eacc[8];
            #pragma unroll
            for (int j = 0; j < 8; ++j) { dacc[j] = 0.f; eacc[j] = 0.f; }
            for (int d4 = 0; d4 < 16; ++d4) {
                float x0 = __shfl(xv, d4 * 4 + 0), x1 = __shfl(xv, d4 * 4 + 1);
                float x2 = __shfl(xv, d4 * 4 + 2), x3 = __shfl(xv, d4 * 4 + 3);
                #pragma unroll
                for (int j = 0; j < 8; ++j) {
                    const int k = lane + 64 * (half * 8 + j);
                    float4 e = e4[k * 16 + d4];
                    dacc[j] = fmaf(x0, e.x, dacc[j]); dacc[j] = fmaf(x1, e.y, dacc[j]);
                    dacc[j] = fmaf(x2, e.z, dacc[j]); dacc[j] = fmaf(x3, e.w, dacc[j]);
                    eacc[j] = fmaf(e.x, e.x, eacc[j]); eacc[j] = fmaf(e.y, e.y, eacc[j]);
                    eacc[j] = fmaf(e.z, e.z, eacc[j]); eacc[j] = fmaf(e.w, e.w, eacc[j]);
                }
            }
            #pragma unroll
            for (int j = 0; j < 8; ++j) {              // k ascending per lane: first-min kept
                const int k = lane + 64 * (half * 8 + j);
                float v = fmaf(0.5f, eacc[j], -dacc[j]);
                if (v < bv) { bv = v; bk = k; }
            }
        }
        #pragma unroll
        for (int st = 32; st; st >>= 1) {              // 64-wide (v, k) argmin, k tie-break
            float ov = __shfl_xor(bv, st);
            int   ok = __shfl_xor(bk, st);
            if (ov < bv || (ov == bv && ok < bk)) { bv = ov; bk = ok; }
        }
        if (lane == 0) si1[p] = bk;
    }
    __syncthreads();

    // ---- final: indices, quantized gather-write, loss — all 256 threads
    {
        const int p = tid & 63, dg = tid >> 6;         // dims dg*16 .. dg*16+15
        const int bi = si1[p];
        if (dg == 0) out[IOFF + n0 + p] = (float)bi;
        const float* e = emb + (size_t)bi * DIMS;
        const float* xp = xbase + p;
        float* oq = out + QOFF + (size_t)b * (DIMS * HW) + off + p;
        float ls = 0.f;
        #pragma unroll
        for (int d0 = 0; d0 < 16; ++d0) {
            const int d = dg * 16 + d0;
            float ev = e[d];
            float xv = xp[d * HW];
            float df = ev - xv;
            ls = fmaf(df, df, ls);
            oq[d * HW] = ev;                           // coalesced across point-threads
        }
        #pragma unroll
        for (int st = 32; st; st >>= 1) ls += __shfl_down(ls, st);
        if (lane == 0) lred[w] = ls;
    }
    __syncthreads();
    if (tid == 0) {
        float s = lred[0] + lred[1] + lred[2] + lred[3];
        atomicAdd(out, s * (0.25f / (float)(NPTS * DIMS)));
    }
}

extern "C" void kernel_launch(void* const* d_in, const int* in_sizes, int n_in,
                              void* d_out, int out_size, void* d_ws, size_t ws_size,
                              hipStream_t stream) {
    const float* in  = (const float*)d_in[0];
    const float* emb = (const float*)d_in[1];
    float* out = (float*)d_out;
    ushort* Eh = (ushort*)d_ws;                        // 131072 B
    ushort* El = (ushort*)((char*)d_ws + 131072);      // 131072 B
    float*  hsq = (float*)((char*)d_ws + 262144);      // 4096 B
    (void)in_sizes; (void)n_in; (void)out_size; (void)ws_size;

    vq_prep<<<64, 256, 0, stream>>>(emb, Eh, El, hsq, out);   // also zeroes out[0]
    vq_main<<<NPTS / NPB, 256, 0, stream>>>(in, emb, Eh, El, hsq, out);
}

// Round 8
// 159.558 us; speedup vs baseline: 1.3439x; 1.3439x over previous
//
#include <hip/hip_runtime.h>

// VQ-VAE vector quantizer, round 8: 32x32x16 MFMA discriminator.
// R3-R7 invariant: ~40-60 cyc per MFMA *instruction* regardless of memory structure ->
// test per-instruction-overhead theory by 4x FLOP/instr: v_mfma_f32_32x32x16_bf16.
// One 32x32 (points x codes) tile per wave per group, 12-MFMA chain (hh+hl+lh over K=64).
// C/D layout (measured m74/m101): col=lane&31, row=(reg&3)+8*(reg>>2)+4*(lane>>5).
// A/B k-mapping: k = 8*(lane>>5)+j (block-contiguous halves, same family as 16x16x32).
// Structure otherwise = R4 (best so far): NPB=128, 512 blocks, B direct from ws tables,
// exact streaming top-2 per lane, near-ties (gap<1e-3, err bound ~1e-4) rescanned in fp32.
// out (fp32 concat): [ loss(1) | quantized NCHW (4194304) | indices as float (65536) ]

#define DIMS   64
#define HW     4096
#define NPTS   65536
#define NCODES 1024
#define NPB    128
#define QOFF   1
#define IOFF   (1 + NPTS * DIMS)
#define EPSGAP 1.0e-3f

typedef unsigned int uint;
typedef unsigned short ushort;
typedef unsigned long long ull;
typedef __attribute__((ext_vector_type(8))) short short8;
typedef __attribute__((ext_vector_type(16))) float f32x16;

__device__ __forceinline__ ushort bf16_rne(float f) {
    uint u = __float_as_uint(f);
    uint r = u + 0x7FFFu + ((u >> 16) & 1u);
    return (ushort)(r >> 16);
}
__device__ __forceinline__ float bf16f(ushort h) { return __uint_as_float(((uint)h) << 16); }

// ---- prep: emb fp32 -> {Eh, El bf16 [1024][64]}, hsq = 0.5||e||^2, zero out[0]
__global__ void vq_prep(const float* __restrict__ emb, ushort* __restrict__ Eh,
                        ushort* __restrict__ El, float* __restrict__ hsq,
                        float* __restrict__ out)
{
    const int t = blockIdx.x * 256 + threadIdx.x;      // 0..16383, one float4 each
    if (t == 0) out[0] = 0.f;
    float4 v = ((const float4*)emb)[t];
    ushort h0 = bf16_rne(v.x), h1 = bf16_rne(v.y), h2 = bf16_rne(v.z), h3 = bf16_rne(v.w);
    ushort l0 = bf16_rne(v.x - bf16f(h0)), l1 = bf16_rne(v.y - bf16f(h1));
    ushort l2 = bf16_rne(v.z - bf16f(h2)), l3 = bf16_rne(v.w - bf16f(h3));
    uint2 hp, lp;
    hp.x = (uint)h0 | ((uint)h1 << 16); hp.y = (uint)h2 | ((uint)h3 << 16);
    lp.x = (uint)l0 | ((uint)l1 << 16); lp.y = (uint)l2 | ((uint)l3 << 16);
    *(uint2*)(Eh + (size_t)t * 4) = hp;
    *(uint2*)(El + (size_t)t * 4) = lp;
    if (t < NCODES) {
        const float4* r = (const float4*)(emb + (size_t)t * DIMS);
        float s = 0.f;
        #pragma unroll
        for (int i = 0; i < 16; ++i) {
            float4 e = r[i];
            s = fmaf(e.x, e.x, s); s = fmaf(e.y, e.y, s);
            s = fmaf(e.z, e.z, s); s = fmaf(e.w, e.w, s);
        }
        hsq[t] = 0.5f * s;
    }
}

__launch_bounds__(256, 2)
__global__ void vq_main(const float* __restrict__ in, const float* __restrict__ emb,
                        const ushort* __restrict__ Ehw, const ushort* __restrict__ Elw,
                        const float* __restrict__ hsqw, float* __restrict__ out)
{
    __shared__ float sv1[NPB];
    __shared__ float sv2[NPB];
    __shared__ int   si1[NPB];
    __shared__ ull   msk[2];
    __shared__ int   lst[1 + NPB];
    __shared__ float lred[4];

    const int tid = threadIdx.x;
    const int lane = tid & 63, w = tid >> 6;
    const int nn = lane & 31;                          // row (A) / col (B) within 32
    const int h  = lane >> 5;                          // k-half selector
    const int n0 = blockIdx.x * NPB;
    const int b = n0 >> 12, off = n0 & 4095;           // 128 | 4096: never crosses a batch
    const float* xbase = in + (size_t)b * (DIMS * HW) + off;

    // ---- A fragments: wave's 32 points, K=64 in 4 K16-steps; k = ks*16 + 8h + j
    short8 Ah[4], Al[4];
    {
        const int p = w * 32 + nn;
        #pragma unroll
        for (int ks = 0; ks < 4; ++ks) {
            union { ushort u[8]; short8 v; } th, tl;
            #pragma unroll
            for (int j = 0; j < 8; ++j) {
                float x = xbase[(ks * 16 + h * 8 + j) * HW + p];
                ushort hh = bf16_rne(x);
                th.u[j] = hh;
                tl.u[j] = bf16_rne(x - bf16f(hh));
            }
            Ah[ks] = th.v; Al[ks] = tl.v;
        }
    }

    float v1s[16], v2s[16]; int i1s[16];
    #pragma unroll
    for (int r = 0; r < 16; ++r) { v1s[r] = 1e30f; v2s[r] = 1e30f; i1s[r] = 0; }

    // ---- K-loop: 32 groups of 32 codes; one 32x32 tile = 12 MFMA (hh+hl+lh, K=64)
    for (int g = 0; g < 32; ++g) {
        const int ca = g * 32 + nn;                    // this lane's code id
        const ushort* eb = Ehw + (size_t)ca * 64 + h * 8;
        const ushort* lb = Elw + (size_t)ca * 64 + h * 8;
        short8 Bh[4], Bl[4];
        #pragma unroll
        for (int ks = 0; ks < 4; ++ks) {
            Bh[ks] = *(const short8*)(eb + ks * 16);
            Bl[ks] = *(const short8*)(lb + ks * 16);
        }
        const float ha = hsqw[ca];
        f32x16 acc = {0.f,0.f,0.f,0.f,0.f,0.f,0.f,0.f,0.f,0.f,0.f,0.f,0.f,0.f,0.f,0.f};
        #pragma unroll
        for (int ks = 0; ks < 4; ++ks)
            acc = __builtin_amdgcn_mfma_f32_32x32x16_bf16(Ah[ks], Bh[ks], acc, 0, 0, 0);
        #pragma unroll
        for (int ks = 0; ks < 4; ++ks)
            acc = __builtin_amdgcn_mfma_f32_32x32x16_bf16(Ah[ks], Bl[ks], acc, 0, 0, 0);
        #pragma unroll
        for (int ks = 0; ks < 4; ++ks)
            acc = __builtin_amdgcn_mfma_f32_32x32x16_bf16(Al[ks], Bh[ks], acc, 0, 0, 0);
        #pragma unroll
        for (int r = 0; r < 16; ++r) {                 // r -> point row (fixed lane->code)
            float d = ha - acc[r];
            v2s[r] = fminf(v2s[r], fmaxf(d, v1s[r])); // exact streaming 2nd-min
            bool c2 = d < v1s[r];                      // strict: ascending g keeps lowest idx
            i1s[r] = c2 ? ca : i1s[r];
            v1s[r] = fminf(d, v1s[r]);
        }
    }

    // ---- merge across the 32 code-lanes (xor strides stay within each 32-lane half,
    //      and both halves of a point's codes live in the same half-wave)
    #pragma unroll
    for (int st = 1; st < 32; st <<= 1) {
        #pragma unroll
        for (int r = 0; r < 16; ++r) {
            float ov1 = __shfl_xor(v1s[r], st);
            float ov2 = __shfl_xor(v2s[r], st);
            int   oi1 = __shfl_xor(i1s[r], st);
            v2s[r] = fminf(fminf(v2s[r], ov2), fmaxf(v1s[r], ov1));
            bool c = (ov1 < v1s[r]) || (ov1 == v1s[r] && oi1 < i1s[r]);
            if (c) i1s[r] = oi1;
            v1s[r] = fminf(v1s[r], ov1);
        }
    }
    if (nn == 0) {                                     // lanes 0 and 32 hold 16 rows each
        #pragma unroll
        for (int r = 0; r < 16; ++r) {
            const int row = (r & 3) + 8 * (r >> 2) + 4 * h;
            const int p = w * 32 + row;
            sv1[p] = v1s[r]; si1[p] = i1s[r]; sv2[p] = v2s[r];
        }
    }
    __syncthreads();

    // ---- flag near-ties (waves 0,1 cover points 0..127)
    {
        bool f = (tid < NPB) && ((sv2[tid] - sv1[tid]) < EPSGAP);
        ull bm = __ballot(f);
        if (lane == 0 && w < 2) msk[w] = bm;
    }
    __syncthreads();
    if (tid == 0) {
        int c = 0;
        ull m0 = msk[0];
        while (m0) { lst[1 + c++] = __ffsll(m0) - 1; m0 &= m0 - 1; }
        ull m1 = msk[1];
        while (m1) { lst[1 + c++] = 64 + (__ffsll(m1) - 1); m1 &= m1 - 1; }
        lst[0] = c;
    }
    __syncthreads();

    // ---- exact fp32 rescan, one wave per flagged point (rare: gap < 1e-3)
    const int cnt = lst[0];
    const float4* e4 = (const float4*)emb;
    for (int it = w; it < cnt; it += 4) {
        const int p = lst[1 + it];
        float xv = xbase[lane * HW + p];               // lane d holds x_d (exact fp32)
        float bv = 1e30f; int bk = 0;
        #pragma unroll
        for (int half = 0; half < 2; ++half) {
            float dacc[8];
            #pragma unroll
            for (int j = 0; j < 8; ++j) dacc[j] = 0.f;
            for (int d4 = 0; d4 < 16; ++d4) {
                float x0 = __shfl(xv, d4 * 4 + 0), x1 = __shfl(xv, d4 * 4 + 1);
                float x2 = __shfl(xv, d4 * 4 + 2), x3 = __shfl(xv, d4 * 4 + 3);
                #pragma unroll
                for (int j = 0; j < 8; ++j) {
                    const int k = lane + 64 * (half * 8 + j);
                    float4 e = e4[k * 16 + d4];
                    dacc[j] = fmaf(x0, e.x, dacc[j]); dacc[j] = fmaf(x1, e.y, dacc[j]);
                    dacc[j] = fmaf(x2, e.z, dacc[j]); dacc[j] = fmaf(x3, e.w, dacc[j]);
                }
            }
            #pragma unroll
            for (int j = 0; j < 8; ++j) {              // ascending k per lane: first-min kept
                const int k = lane + 64 * (half * 8 + j);
                float v = hsqw[k] - dacc[j];
                if (v < bv) { bv = v; bk = k; }
            }
        }
        #pragma unroll
        for (int st = 32; st; st >>= 1) {              // 64-wide (v, k) argmin, k tie-break
            float ov = __shfl_xor(bv, st);
            int   ok = __shfl_xor(bk, st);
            if (ov < bv || (ov == bv && ok < bk)) { bv = ov; bk = ok; }
        }
        if (lane == 0) si1[p] = bk;
    }
    __syncthreads();

    // ---- final: indices, quantized gather-write, loss — all 256 threads (32 dims each)
    {
        const int p = tid & 127, dg = tid >> 7;
        const int bi = si1[p];
        if (dg == 0) out[IOFF + n0 + p] = (float)bi;
        const float* e = emb + (size_t)bi * DIMS;
        const float* xp = xbase + p;
        float* oq = out + QOFF + (size_t)b * (DIMS * HW) + off + p;
        float ls = 0.f;
        #pragma unroll
        for (int d0 = 0; d0 < 32; ++d0) {
            const int d = dg * 32 + d0;
            float ev = e[d];
            float xv = xp[d * HW];
            float df = ev - xv;
            ls = fmaf(df, df, ls);
            oq[d * HW] = ev;                           // coalesced across point-threads
        }
        #pragma unroll
        for (int st = 32; st; st >>= 1) ls += __shfl_down(ls, st);
        if (lane == 0) lred[w] = ls;
    }
    __syncthreads();
    if (tid == 0) {
        float s = lred[0] + lred[1] + lred[2] + lred[3];
        atomicAdd(out, s * (0.25f / (float)(NPTS * DIMS)));
    }
}

extern "C" void kernel_launch(void* const* d_in, const int* in_sizes, int n_in,
                              void* d_out, int out_size, void* d_ws, size_t ws_size,
                              hipStream_t stream) {
    const float* in  = (const float*)d_in[0];
    const float* emb = (const float*)d_in[1];
    float* out = (float*)d_out;
    ushort* Eh = (ushort*)d_ws;                        // 131072 B
    ushort* El = (ushort*)((char*)d_ws + 131072);      // 131072 B
    float*  hsq = (float*)((char*)d_ws + 262144);      // 4096 B
    (void)in_sizes; (void)n_in; (void)out_size; (void)ws_size;

    vq_prep<<<64, 256, 0, stream>>>(emb, Eh, El, hsq, out);   // also zeroes out[0]
    vq_main<<<NPTS / NPB, 256, 0, stream>>>(in, emb, Eh, El, hsq, out);
}

// Round 9
// 158.471 us; speedup vs baseline: 1.3531x; 1.0069x over previous
//
#include <hip/hip_runtime.h>

// VQ-VAE vector quantizer, round 9: independent-MFMA-chain discriminator.
// R3-R8 invariant: ~100us regardless of MFMA count/ILP(<=2)/memory path; all had <=2
// independent acc chains 6-12 deep per wave. Theory: dependent-MFMA latency at 2 waves/SIMD
// is the wall. This round: 16x16x32 tiles, SIX independent 2-deep chains per point-subtile
// (hh0->hh1, hl0->hl1, lh0->lh1), 12 independent MFMAs in flight per 16-code group; partial
// sums combined in VALU. Skeleton otherwise identical to R8 (NPB=128, 512 blocks, B direct
// from ws tables, exact streaming top-2, near-tie fp32 rescan).
// out (fp32 concat): [ loss(1) | quantized NCHW (4194304) | indices as float (65536) ]

#define DIMS   64
#define HW     4096
#define NPTS   65536
#define NCODES 1024
#define NPB    128
#define QOFF   1
#define IOFF   (1 + NPTS * DIMS)
#define EPSGAP 1.0e-3f

typedef unsigned int uint;
typedef unsigned short ushort;
typedef unsigned long long ull;
typedef __attribute__((ext_vector_type(8))) short short8;
typedef __attribute__((ext_vector_type(4))) float f32x4;

__device__ __forceinline__ ushort bf16_rne(float f) {
    uint u = __float_as_uint(f);
    uint r = u + 0x7FFFu + ((u >> 16) & 1u);
    return (ushort)(r >> 16);
}
__device__ __forceinline__ float bf16f(ushort h) { return __uint_as_float(((uint)h) << 16); }

// ---- prep: emb fp32 -> {Eh, El bf16 [1024][64]}, hsq = 0.5||e||^2, zero out[0]
__global__ void vq_prep(const float* __restrict__ emb, ushort* __restrict__ Eh,
                        ushort* __restrict__ El, float* __restrict__ hsq,
                        float* __restrict__ out)
{
    const int t = blockIdx.x * 256 + threadIdx.x;      // 0..16383, one float4 each
    if (t == 0) out[0] = 0.f;
    float4 v = ((const float4*)emb)[t];
    ushort h0 = bf16_rne(v.x), h1 = bf16_rne(v.y), h2 = bf16_rne(v.z), h3 = bf16_rne(v.w);
    ushort l0 = bf16_rne(v.x - bf16f(h0)), l1 = bf16_rne(v.y - bf16f(h1));
    ushort l2 = bf16_rne(v.z - bf16f(h2)), l3 = bf16_rne(v.w - bf16f(h3));
    uint2 hp, lp;
    hp.x = (uint)h0 | ((uint)h1 << 16); hp.y = (uint)h2 | ((uint)h3 << 16);
    lp.x = (uint)l0 | ((uint)l1 << 16); lp.y = (uint)l2 | ((uint)l3 << 16);
    *(uint2*)(Eh + (size_t)t * 4) = hp;
    *(uint2*)(El + (size_t)t * 4) = lp;
    if (t < NCODES) {
        const float4* r = (const float4*)(emb + (size_t)t * DIMS);
        float s = 0.f;
        #pragma unroll
        for (int i = 0; i < 16; ++i) {
            float4 e = r[i];
            s = fmaf(e.x, e.x, s); s = fmaf(e.y, e.y, s);
            s = fmaf(e.z, e.z, s); s = fmaf(e.w, e.w, s);
        }
        hsq[t] = 0.5f * s;
    }
}

__launch_bounds__(256, 2)
__global__ void vq_main(const float* __restrict__ in, const float* __restrict__ emb,
                        const ushort* __restrict__ Ehw, const ushort* __restrict__ Elw,
                        const float* __restrict__ hsqw, float* __restrict__ out)
{
    __shared__ float sv1[NPB];
    __shared__ float sv2[NPB];
    __shared__ int   si1[NPB];
    __shared__ ull   msk[2];
    __shared__ int   lst[1 + NPB];
    __shared__ float lred[4];

    const int tid = threadIdx.x;
    const int lane = tid & 63, w = tid >> 6;
    const int m = lane & 15, quad = lane >> 4;
    const int n0 = blockIdx.x * NPB;
    const int b = n0 >> 12, off = n0 & 4095;           // 128 | 4096: never crosses a batch
    const float* xbase = in + (size_t)b * (DIMS * HW) + off;

    // ---- A fragments: wave's 32 points as 2 subtiles of 16; K=64 in 2 K32-steps.
    //      frag layout (verified): A[row=m][k = ks*32 + quad*8 + j]
    short8 Ah[2][2], Al[2][2];
    #pragma unroll
    for (int pt = 0; pt < 2; ++pt) {
        const int p = w * 32 + pt * 16 + m;
        #pragma unroll
        for (int ks = 0; ks < 2; ++ks) {
            union { ushort u[8]; short8 v; } th, tl;
            #pragma unroll
            for (int j = 0; j < 8; ++j) {
                float x = xbase[(ks * 32 + quad * 8 + j) * HW + p];
                ushort hh = bf16_rne(x);
                th.u[j] = hh;
                tl.u[j] = bf16_rne(x - bf16f(hh));
            }
            Ah[pt][ks] = th.v; Al[pt][ks] = tl.v;
        }
    }

    float v1s[8], v2s[8]; int i1s[8];                  // [pt*4 + r]
    #pragma unroll
    for (int s = 0; s < 8; ++s) { v1s[s] = 1e30f; v2s[s] = 1e30f; i1s[s] = 0; }

    // ---- K-loop: 64 groups of 16 codes; per group 12 MFMAs in 6 independent 2-deep chains
    for (int g = 0; g < 64; ++g) {
        const int ca = g * 16 + m;                     // this lane's code id
        const ushort* eb = Ehw + (size_t)ca * 64 + quad * 8;
        const ushort* lb = Elw + (size_t)ca * 64 + quad * 8;
        short8 Bh0 = *(const short8*)(eb);
        short8 Bh1 = *(const short8*)(eb + 32);
        short8 Bl0 = *(const short8*)(lb);
        short8 Bl1 = *(const short8*)(lb + 32);
        const float ha = hsqw[ca];

        const f32x4 z = {0.f, 0.f, 0.f, 0.f};
        f32x4 chh[2], chl[2], clh[2];
        // six independent chains, each exactly 2 deep (ks0 -> ks1)
        chh[0] = __builtin_amdgcn_mfma_f32_16x16x32_bf16(Ah[0][0], Bh0, z, 0, 0, 0);
        chl[0] = __builtin_amdgcn_mfma_f32_16x16x32_bf16(Ah[0][0], Bl0, z, 0, 0, 0);
        clh[0] = __builtin_amdgcn_mfma_f32_16x16x32_bf16(Al[0][0], Bh0, z, 0, 0, 0);
        chh[1] = __builtin_amdgcn_mfma_f32_16x16x32_bf16(Ah[1][0], Bh0, z, 0, 0, 0);
        chl[1] = __builtin_amdgcn_mfma_f32_16x16x32_bf16(Ah[1][0], Bl0, z, 0, 0, 0);
        clh[1] = __builtin_amdgcn_mfma_f32_16x16x32_bf16(Al[1][0], Bh0, z, 0, 0, 0);
        chh[0] = __builtin_amdgcn_mfma_f32_16x16x32_bf16(Ah[0][1], Bh1, chh[0], 0, 0, 0);
        chl[0] = __builtin_amdgcn_mfma_f32_16x16x32_bf16(Ah[0][1], Bl1, chl[0], 0, 0, 0);
        clh[0] = __builtin_amdgcn_mfma_f32_16x16x32_bf16(Al[0][1], Bh1, clh[0], 0, 0, 0);
        chh[1] = __builtin_amdgcn_mfma_f32_16x16x32_bf16(Ah[1][1], Bh1, chh[1], 0, 0, 0);
        chl[1] = __builtin_amdgcn_mfma_f32_16x16x32_bf16(Ah[1][1], Bl1, chl[1], 0, 0, 0);
        clh[1] = __builtin_amdgcn_mfma_f32_16x16x32_bf16(Al[1][1], Bh1, clh[1], 0, 0, 0);

        #pragma unroll
        for (int pt = 0; pt < 2; ++pt) {
            #pragma unroll
            for (int r = 0; r < 4; ++r) {              // point = w*32 + pt*16 + quad*4 + r
                const int s = pt * 4 + r;
                float d = ha - (chh[pt][r] + (chl[pt][r] + clh[pt][r]));
                v2s[s] = fminf(v2s[s], fmaxf(d, v1s[s]));   // exact streaming 2nd-min
                bool c2 = d < v1s[s];                  // strict: ascending g keeps lowest idx
                i1s[s] = c2 ? ca : i1s[s];
                v1s[s] = fminf(d, v1s[s]);
            }
        }
    }

    // ---- merge across the 16 code-lanes (xor shuffle within 16-lane groups)
    #pragma unroll
    for (int st = 1; st < 16; st <<= 1) {
        #pragma unroll
        for (int s = 0; s < 8; ++s) {
            float ov1 = __shfl_xor(v1s[s], st);
            float ov2 = __shfl_xor(v2s[s], st);
            int   oi1 = __shfl_xor(i1s[s], st);
            v2s[s] = fminf(fminf(v2s[s], ov2), fmaxf(v1s[s], ov1));
            bool c = (ov1 < v1s[s]) || (ov1 == v1s[s] && oi1 < i1s[s]);
            if (c) i1s[s] = oi1;
            v1s[s] = fminf(v1s[s], ov1);
        }
    }
    if (m == 0) {                                      // lanes 0,16,32,48: 8 points each
        #pragma unroll
        for (int s = 0; s < 8; ++s) {
            const int pt = s >> 2, r = s & 3;
            const int p = w * 32 + pt * 16 + quad * 4 + r;
            sv1[p] = v1s[s]; si1[p] = i1s[s]; sv2[p] = v2s[s];
        }
    }
    __syncthreads();

    // ---- flag near-ties (waves 0,1 cover points 0..127)
    {
        bool f = (tid < NPB) && ((sv2[tid] - sv1[tid]) < EPSGAP);
        ull bm = __ballot(f);
        if (lane == 0 && w < 2) msk[w] = bm;
    }
    __syncthreads();
    if (tid == 0) {
        int c = 0;
        ull m0 = msk[0];
        while (m0) { lst[1 + c++] = __ffsll(m0) - 1; m0 &= m0 - 1; }
        ull m1 = msk[1];
        while (m1) { lst[1 + c++] = 64 + (__ffsll(m1) - 1); m1 &= m1 - 1; }
        lst[0] = c;
    }
    __syncthreads();

    // ---- exact fp32 rescan, one wave per flagged point (rare: gap < 1e-3)
    const int cnt = lst[0];
    const float4* e4 = (const float4*)emb;
    for (int it = w; it < cnt; it += 4) {
        const int p = lst[1 + it];
        float xv = xbase[lane * HW + p];               // lane d holds x_d (exact fp32)
        float bv = 1e30f; int bk = 0;
        #pragma unroll
        for (int half = 0; half < 2; ++half) {
            float dacc[8];
            #pragma unroll
            for (int j = 0; j < 8; ++j) dacc[j] = 0.f;
            for (int d4 = 0; d4 < 16; ++d4) {
                float x0 = __shfl(xv, d4 * 4 + 0), x1 = __shfl(xv, d4 * 4 + 1);
                float x2 = __shfl(xv, d4 * 4 + 2), x3 = __shfl(xv, d4 * 4 + 3);
                #pragma unroll
                for (int j = 0; j < 8; ++j) {
                    const int k = lane + 64 * (half * 8 + j);
                    float4 e = e4[k * 16 + d4];
                    dacc[j] = fmaf(x0, e.x, dacc[j]); dacc[j] = fmaf(x1, e.y, dacc[j]);
                    dacc[j] = fmaf(x2, e.z, dacc[j]); dacc[j] = fmaf(x3, e.w, dacc[j]);
                }
            }
            #pragma unroll
            for (int j = 0; j < 8; ++j) {              // ascending k per lane: first-min kept
                const int k = lane + 64 * (half * 8 + j);
                float v = hsqw[k] - dacc[j];
                if (v < bv) { bv = v; bk = k; }
            }
        }
        #pragma unroll
        for (int st = 32; st; st >>= 1) {              // 64-wide (v, k) argmin, k tie-break
            float ov = __shfl_xor(bv, st);
            int   ok = __shfl_xor(bk, st);
            if (ov < bv || (ov == bv && ok < bk)) { bv = ov; bk = ok; }
        }
        if (lane == 0) si1[p] = bk;
    }
    __syncthreads();

    // ---- final: indices, quantized gather-write, loss — all 256 threads (32 dims each)
    {
        const int p = tid & 127, dg = tid >> 7;
        const int bi = si1[p];
        if (dg == 0) out[IOFF + n0 + p] = (float)bi;
        const float* e = emb + (size_t)bi * DIMS;
        const float* xp = xbase + p;
        float* oq = out + QOFF + (size_t)b * (DIMS * HW) + off + p;
        float ls = 0.f;
        #pragma unroll
        for (int d0 = 0; d0 < 32; ++d0) {
            const int d = dg * 32 + d0;
            float ev = e[d];
            float xv = xp[d * HW];
            float df = ev - xv;
            ls = fmaf(df, df, ls);
            oq[d * HW] = ev;                           // coalesced across point-threads
        }
        #pragma unroll
        for (int st = 32; st; st >>= 1) ls += __shfl_down(ls, st);
        if (lane == 0) lred[w] = ls;
    }
    __syncthreads();
    if (tid == 0) {
        float s = lred[0] + lred[1] + lred[2] + lred[3];
        atomicAdd(out, s * (0.25f / (float)(NPTS * DIMS)));
    }
}

extern "C" void kernel_launch(void* const* d_in, const int* in_sizes, int n_in,
                              void* d_out, int out_size, void* d_ws, size_t ws_size,
                              hipStream_t stream) {
    const float* in  = (const float*)d_in[0];
    const float* emb = (const float*)d_in[1];
    float* out = (float*)d_out;
    ushort* Eh = (ushort*)d_ws;                        // 131072 B
    ushort* El = (ushort*)((char*)d_ws + 131072);      // 131072 B
    float*  hsq = (float*)((char*)d_ws + 262144);      // 4096 B
    (void)in_sizes; (void)n_in; (void)out_size; (void)ws_size;

    vq_prep<<<64, 256, 0, stream>>>(emb, Eh, El, hsq, out);   // also zeroes out[0]
    vq_main<<<NPTS / NPB, 256, 0, stream>>>(in, emb, Eh, El, hsq, out);
}